// Round 12
// baseline (119.529 us; speedup 1.0000x reference)
//
#include <hip/hip_runtime.h>
#include <hip/hip_bf16.h>
#include <math.h>

#define KC 32
#define DC 128
#define QC 16
#define NPTS 20000

// ws layout (bytes):
//   c2p[32] f32        @ 0
//   btG[544*128] bf16  @ 128     (rows 0..511 = G/sqrt2, 512..543 = w')
//   s2h[20000] f32     @ 139392  (0.5 * x^T invpsi x)
//   cnt[313] int       @ 219392  (row-tile completion counters)
//   XH[1250*2048] s    @ 220672  (fragment-major bf16 X)
#define WS_C2P_B 0
#define WS_BTG_B 128
#define WS_S2_B  139392
#define WS_CNT_B 219392
#define WS_XH_B  220672

typedef __attribute__((ext_vector_type(8))) short bf16x8;
typedef __attribute__((ext_vector_type(4))) float f32x4;

// round-to-nearest-even bf16
static __device__ __forceinline__ short f2bf(float x) {
    union { float f; unsigned u; } v; v.f = x;
    unsigned r = v.u + 0x7fffu + ((v.u >> 16) & 1u);
    return (short)(r >> 16);
}

// ---------------------------------------------------------------------------
// Kernel 1 (fused prep): blocks 0..31 per-component Woodbury precompute
// (G/sqrt2 + w' rows, single-plane bf16; C2'); blocks 32+ convert 64 X rows
// each to bf16 fragment-major, store 0.5*x^T invpsi x, and zero cnt[xb].
// ---------------------------------------------------------------------------
__global__ __launch_bounds__(256) void mfa_prep(
    const float* __restrict__ X, const float* __restrict__ log_pi,
    const float* __restrict__ mu, const float* __restrict__ Lam,
    const float* __restrict__ log_psi,
    float* __restrict__ c2p, short* __restrict__ btG,
    short* __restrict__ xH, float* __restrict__ s2g, int* __restrict__ cnt)
{
    int t = threadIdx.x;
    if (blockIdx.x >= KC) {
        // ---- conversion path ----
        int xb = blockIdx.x - KC;          // 0..312
        if (t == 0) cnt[xb] = 0;
        int cseg = t & 15, rloc = t >> 4;
        int c0 = cseg * 8;
        float is[8];
#pragma unroll
        for (int j = 0; j < 8; j++) {
            float psi = expf(log_psi[c0 + j]) + 1e-5f + 1e-4f;
            is[j] = 1.0f / psi;
        }
#pragma unroll
        for (int p = 0; p < 4; p++) {
            int r = xb*64 + p*16 + rloc;
            if (r < NPTS) {
                float xs[8];
                const float* xp = X + (size_t)r*DC + c0;
                *(float4*)&xs[0] = *(const float4*)xp;
                *(float4*)&xs[4] = *(const float4*)(xp + 4);
                bf16x8 hv;
                float s2 = 0.f;
#pragma unroll
                for (int j = 0; j < 8; j++) {
                    hv[j] = f2bf(xs[j]);
                    s2 = fmaf(xs[j]*is[j], xs[j], s2);
                }
                size_t fa = (size_t)(r >> 4)*2048 + (size_t)(cseg >> 2)*512
                          + (size_t)(cseg & 3)*128 + (size_t)(r & 15)*8;
                *(bf16x8*)(xH + fa) = hv;
                s2 += __shfl_xor(s2, 1, 16);
                s2 += __shfl_xor(s2, 2, 16);
                s2 += __shfl_xor(s2, 4, 16);
                s2 += __shfl_xor(s2, 8, 16);
                if (cseg == 0) s2g[r] = 0.5f * s2;
            }
        }
        return;
    }
    // ---- per-component Woodbury path ----
    int k = blockIdx.x;
    __shared__ float invpsiS[DC], muS[DC];
    __shared__ float lamR[DC*17];
    __shared__ float lamSc[DC*17];
    __shared__ float MS[QC*QC], LSm[QC*QC];
    __shared__ float invDS[QC];
    __shared__ float GT[QC*129];
    __shared__ float hS[QC];
    __shared__ float redS[4];
    __shared__ float hhS, ldS;

    float lp = 0.f, ipm = 0.f;
    if (t < DC) {
        float psi = expf(log_psi[t]) + 1e-5f + 1e-4f;
        float ip = 1.0f / psi;
        invpsiS[t] = ip;
        lp = logf(psi);
        float m = mu[k*DC + t];
        muS[t] = m;
        ipm = ip*m*m;
    }
    __syncthreads();
    for (int e = t; e < DC*QC; e += 256) {
        int d = e >> 4, q = e & 15;
        float lv = Lam[k*DC*QC + e];
        lamR[d*17 + q]  = lv;
        lamSc[d*17 + q] = lv * invpsiS[d];
    }
    __syncthreads();
    {   // M = I + Lam^T diag(invpsi) Lam
        int q = t >> 4, r = t & 15;
        float s0 = (q == r) ? 1.0f : 0.0f, s1 = 0.f, s2 = 0.f, s3 = 0.f;
#pragma unroll 1
        for (int d = 0; d < DC; d += 4) {
            s0 = fmaf(lamSc[(d+0)*17 + q], lamR[(d+0)*17 + r], s0);
            s1 = fmaf(lamSc[(d+1)*17 + q], lamR[(d+1)*17 + r], s1);
            s2 = fmaf(lamSc[(d+2)*17 + q], lamR[(d+2)*17 + r], s2);
            s3 = fmaf(lamSc[(d+3)*17 + q], lamR[(d+3)*17 + r], s3);
        }
        MS[q*QC + r] = (s0 + s1) + (s2 + s3);
    }
    __syncthreads();
    if (t < QC) {       // 16-lane shuffle Cholesky
        float m[QC], lrow[QC];
#pragma unroll
        for (int j = 0; j < QC; j++) m[j] = MS[t*QC + j];
#pragma unroll
        for (int j = 0; j < QC; j++) {
            float piv = __shfl(m[j], j, 16);
            float ljj = sqrtf(piv);
            float lij = m[j] / ljj;
            lrow[j] = lij;
#pragma unroll
            for (int r = j + 1; r < QC; r++)
                m[r] = fmaf(-lij, __shfl(lij, r, 16), m[r]);
        }
#pragma unroll
        for (int j = 0; j < QC; j++) LSm[t*QC + j] = lrow[j];
        invDS[t] = 1.0f / lrow[t];
        float ld = 2.0f * logf(lrow[t]);
        ld += __shfl_xor(ld, 1, 16);
        ld += __shfl_xor(ld, 2, 16);
        ld += __shfl_xor(ld, 4, 16);
        ld += __shfl_xor(ld, 8, 16);
        if (t == 0) ldS = ld;
    }
    __syncthreads();
    float g[QC];
    if (t < DC) {       // forward solve: column t of G
        float b[QC];
#pragma unroll
        for (int q = 0; q < QC; q++) b[q] = lamSc[t*17 + q];
#pragma unroll
        for (int i = 0; i < QC; i++) {
            float s = b[i];
#pragma unroll
            for (int x = 0; x < i; x++)
                s = fmaf(-LSm[i*QC + x], g[x], s);
            g[i] = s * invDS[i];
        }
        const float is2 = 0.70710678118654752f;
#pragma unroll
        for (int q = 0; q < QC; q++) {
            GT[q*129 + t] = g[q];
            btG[(k*QC + q)*DC + t] = f2bf(g[q] * is2);
        }
    }
    __syncthreads();
    if (t < QC) {       // h = G mu
        float s = 0.f;
        for (int d = 0; d < DC; d++)
            s = fmaf(GT[t*129 + d], muS[d], s);
        hS[t] = s;
        float hh = s*s;
        hh += __shfl_xor(hh, 1, 16);
        hh += __shfl_xor(hh, 2, 16);
        hh += __shfl_xor(hh, 4, 16);
        hh += __shfl_xor(hh, 8, 16);
        if (t == 0) hhS = hh;
    }
    {
        float a = lp, b2 = ipm;
#pragma unroll
        for (int off = 1; off < 64; off <<= 1) {
            a  += __shfl_xor(a, off, 64);
            b2 += __shfl_xor(b2, off, 64);
        }
        if (t == 0)  { redS[0] = a; redS[1] = b2; }
        if (t == 64) { redS[2] = a; redS[3] = b2; }
    }
    __syncthreads();
    if (t < DC) {       // w' = invpsi*mu - G^T h
        float gh = 0.f;
#pragma unroll
        for (int q = 0; q < QC; q++) gh = fmaf(g[q], hS[q], gh);
        float wp = invpsiS[t]*muS[t] - gh;
        btG[(512 + k)*DC + t] = f2bf(wp);
    }
    if (t == 0) {
        const float log2pi = 1.8378770664093453f;
        float slp = redS[0] + redS[2];
        float tv  = redS[1] + redS[3];
        c2p[k] = log_pi[k]
            - 0.5f*((float)DC*log2pi + slp + ldS + tv) + 0.5f*hhS;
    }
}

// ---------------------------------------------------------------------------
// Kernel 2: MFMA GEMM + fused logsumexp. 2504 blocks.
// XCD-affine map: lin = (wg&7)*313 + (wg>>3); xb = lin>>3, yb = lin&7 —
// same-XCD blocks share contiguous xb (A L1/L2-hot) + full B panel L2-hot.
// Block = 4 waves x 16 rows x 5 N-tiles, single-plane bf16 (20 MFMA/wave).
// LDS = 80 rows x 256B = 20 KB, XOR-swizzled. After writing its 4 comps the
// block bumps cnt[xb]; the 8th block logsumexp-normalizes the 64-row tile.
// ---------------------------------------------------------------------------
#define LH 20480     // 80*256 bytes

__global__ __launch_bounds__(256, 4) void mfa_gemm(
    const short* __restrict__ xH, const float* __restrict__ s2g,
    const float* __restrict__ c2p, const short* __restrict__ btG,
    int* __restrict__ cnt, float* __restrict__ out)
{
    __shared__ __align__(16) char lds[LH];
    __shared__ int lastS;
    int t = threadIdx.x;
    int wg = blockIdx.x;
    int lin = (wg & 7)*313 + (wg >> 3);
    int xb = lin >> 3, yb = lin & 7;

    // stage B panel: 1280 chunks, 5 per thread
    bf16x8 rh[5];
#pragma unroll
    for (int i = 0; i < 5; i++) {
        int s = t + i*256;
        int row = s >> 4, seg = s & 15;
        int gr = (row < 64) ? (yb*64 + row) : (512 + yb*4 + ((row - 64) & 3));
        rh[i] = *(const bf16x8*)(btG + gr*DC + seg*8);
    }

    int l = t & 63, w = t >> 6;
    int m16 = l & 15, g4 = l >> 4;
    int rb0 = xb*64 + w*16;

    // A fragments: fragment-major, wave-uniform clamped tile base (1KB loads)
    int tile16 = min(xb*4 + w, (NPTS >> 4) - 1);
    const short* ph = xH + (size_t)tile16*2048 + g4*128 + m16*8;
    bf16x8 aH[4];
#pragma unroll
    for (int ks = 0; ks < 4; ks++)
        aH[ks] = *(const bf16x8*)(ph + ks*512);
    float s2p = s2g[min(rb0 + m16, NPTS - 1)];

    // swizzled ds_writes
#pragma unroll
    for (int i = 0; i < 5; i++) {
        int s = t + i*256;
        int row = s >> 4, seg = s & 15;
        unsigned bo = ((unsigned)(row*256 + seg*16)) ^ ((unsigned)(row & 7) << 4);
        *(bf16x8*)(lds + bo) = rh[i];
    }
    __syncthreads();

    f32x4 acc[5];
#pragma unroll
    for (int i = 0; i < 5; i++) acc[i] = (f32x4){0.f, 0.f, 0.f, 0.f};
#pragma unroll
    for (int nt = 0; nt < 5; nt++) {
        int row = (nt < 4 ? nt*16 : 64) + m16;
        unsigned rbse = (unsigned)row << 8;
        unsigned sw = (unsigned)(row & 7) << 4;
#pragma unroll
        for (int ks = 0; ks < 4; ks++) {
            unsigned bo = (rbse + (unsigned)((ks*32 + g4*8)*2)) ^ sw;
            bf16x8 bh = *(const bf16x8*)(lds + bo);
            acc[nt] = __builtin_amdgcn_mfma_f32_16x16x32_bf16(aH[ks], bh, acc[nt], 0, 0, 0);
        }
    }

#pragma unroll
    for (int nt = 0; nt < 4; nt++) {
        float c2v = c2p[yb*4 + nt];
#pragma unroll
        for (int j = 0; j < 4; j++) {
            float v = acc[nt][j]*acc[nt][j];
            v += __shfl_xor(v, 1, 64);
            v += __shfl_xor(v, 2, 64);
            v += __shfl_xor(v, 4, 64);
            v += __shfl_xor(v, 8, 64);
            float pv  = __shfl(acc[4][j], (l & 48) | nt, 64);
            float s2j = __shfl(s2p, (l & 48) | (g4*4 + j), 64);
            float lr = c2v + pv - s2j + v;
            int row = rb0 + g4*4 + j;
            if (m16 == 0 && row < NPTS)
                out[(size_t)row*KC + yb*4 + nt] = lr;
        }
    }

    // ---- completion: 8th block for this row-tile does the logsumexp ----
    __syncthreads();                 // drain all lanes' stores (vmcnt 0)
    if (t == 0) {
        int old = __hip_atomic_fetch_add(&cnt[xb], 1, __ATOMIC_ACQ_REL,
                                         __HIP_MEMORY_SCOPE_AGENT);
        lastS = (old == 7);
    }
    __syncthreads();
    if (lastS) {
        int r4 = t >> 2, q4 = t & 3;           // row 0..63, comp-octet 0..3
        int row = xb*64 + r4;
        if (row < NPTS) {
            float v[8];
            float* rp = out + (size_t)row*KC + q4*8;
            *(float4*)&v[0] = *(const float4*)rp;
            *(float4*)&v[4] = *(const float4*)(rp + 4);
            float m = v[0];
#pragma unroll
            for (int j = 1; j < 8; j++) m = fmaxf(m, v[j]);
            m = fmaxf(m, __shfl_xor(m, 1, 64));
            m = fmaxf(m, __shfl_xor(m, 2, 64));
            float s = 0.f;
#pragma unroll
            for (int j = 0; j < 8; j++) s += expf(v[j] - m);
            s += __shfl_xor(s, 1, 64);
            s += __shfl_xor(s, 2, 64);
            float ll = m + logf(s);
#pragma unroll
            for (int j = 0; j < 8; j++) v[j] -= ll;
            *(float4*)rp       = *(const float4*)&v[0];
            *(float4*)(rp + 4) = *(const float4*)&v[4];
            if (q4 == 0) out[(size_t)NPTS*KC + row] = ll;
        }
    }
}

extern "C" void kernel_launch(void* const* d_in, const int* in_sizes, int n_in,
                              void* d_out, int out_size, void* d_ws, size_t ws_size,
                              hipStream_t stream)
{
    const float* X       = (const float*)d_in[0];
    const float* log_pi  = (const float*)d_in[1];
    const float* mu      = (const float*)d_in[2];
    const float* Lam     = (const float*)d_in[3];
    const float* log_psi = (const float*)d_in[4];
    float* out = (float*)d_out;
    char* wsb = (char*)d_ws;
    float* c2p = (float*)(wsb + WS_C2P_B);
    short* btG = (short*)(wsb + WS_BTG_B);
    float* s2g = (float*)(wsb + WS_S2_B);
    int*   cnt = (int*)(wsb + WS_CNT_B);
    short* xH  = (short*)(wsb + WS_XH_B);

    hipLaunchKernelGGL(mfa_prep, dim3(KC + 313), dim3(256), 0, stream,
                       X, log_pi, mu, Lam, log_psi, c2p, btG, xH, s2g, cnt);
    hipLaunchKernelGGL(mfa_gemm, dim3(2504), dim3(256), 0, stream,
                       xH, s2g, c2p, btG, cnt, out);
}

// Round 13
// 41.045 us; speedup vs baseline: 2.9122x; 2.9122x over previous
//
#include <hip/hip_runtime.h>
#include <hip/hip_bf16.h>
#include <math.h>

#define KC 32
#define DC 128
#define QC 16
#define NPTS 20000

// ws layout (bytes):
//   c2p[32] f32        @ 0
//   btG[544*128] bf16  @ 128     (rows 0..511 = G/sqrt2, 512..543 = w')
//   s2h[20000] f32     @ 139392  (0.5 * x^T invpsi x)
//   XH[1250*2048] s    @ 219520  (fragment-major bf16 X)
#define WS_C2P_B 0
#define WS_BTG_B 128
#define WS_S2_B  139392
#define WS_XH_B  219520

typedef __attribute__((ext_vector_type(8))) short bf16x8;
typedef __attribute__((ext_vector_type(4))) float f32x4;

// round-to-nearest-even bf16
static __device__ __forceinline__ short f2bf(float x) {
    union { float f; unsigned u; } v; v.f = x;
    unsigned r = v.u + 0x7fffu + ((v.u >> 16) & 1u);
    return (short)(r >> 16);
}

// ---------------------------------------------------------------------------
// Kernel 1 (fused prep): blocks 0..31 per-component Woodbury precompute
// (G/sqrt2 + w' rows, single-plane bf16; C2'); blocks 32+ convert 64 X rows
// each to bf16 fragment-major and store 0.5*x^T invpsi x.
// ---------------------------------------------------------------------------
__global__ __launch_bounds__(256) void mfa_prep(
    const float* __restrict__ X, const float* __restrict__ log_pi,
    const float* __restrict__ mu, const float* __restrict__ Lam,
    const float* __restrict__ log_psi,
    float* __restrict__ c2p, short* __restrict__ btG,
    short* __restrict__ xH, float* __restrict__ s2g)
{
    int t = threadIdx.x;
    if (blockIdx.x >= KC) {
        // ---- conversion path ----
        int xb = blockIdx.x - KC;          // 0..312
        int cseg = t & 15, rloc = t >> 4;
        int c0 = cseg * 8;
        float is[8];
#pragma unroll
        for (int j = 0; j < 8; j++) {
            float psi = expf(log_psi[c0 + j]) + 1e-5f + 1e-4f;
            is[j] = 1.0f / psi;
        }
#pragma unroll
        for (int p = 0; p < 4; p++) {
            int r = xb*64 + p*16 + rloc;
            if (r < NPTS) {
                float xs[8];
                const float* xp = X + (size_t)r*DC + c0;
                *(float4*)&xs[0] = *(const float4*)xp;
                *(float4*)&xs[4] = *(const float4*)(xp + 4);
                bf16x8 hv;
                float s2 = 0.f;
#pragma unroll
                for (int j = 0; j < 8; j++) {
                    hv[j] = f2bf(xs[j]);
                    s2 = fmaf(xs[j]*is[j], xs[j], s2);
                }
                size_t fa = (size_t)(r >> 4)*2048 + (size_t)(cseg >> 2)*512
                          + (size_t)(cseg & 3)*128 + (size_t)(r & 15)*8;
                *(bf16x8*)(xH + fa) = hv;
                s2 += __shfl_xor(s2, 1, 16);
                s2 += __shfl_xor(s2, 2, 16);
                s2 += __shfl_xor(s2, 4, 16);
                s2 += __shfl_xor(s2, 8, 16);
                if (cseg == 0) s2g[r] = 0.5f * s2;
            }
        }
        return;
    }
    // ---- per-component Woodbury path ----
    int k = blockIdx.x;
    __shared__ float invpsiS[DC], muS[DC];
    __shared__ float lamR[DC*17];
    __shared__ float lamSc[DC*17];
    __shared__ float MS[QC*QC], LSm[QC*QC];
    __shared__ float invDS[QC];
    __shared__ float GT[QC*129];
    __shared__ float hS[QC];
    __shared__ float redS[4];
    __shared__ float hhS, ldS;

    float lp = 0.f, ipm = 0.f;
    if (t < DC) {
        float psi = expf(log_psi[t]) + 1e-5f + 1e-4f;
        float ip = 1.0f / psi;
        invpsiS[t] = ip;
        lp = logf(psi);
        float m = mu[k*DC + t];
        muS[t] = m;
        ipm = ip*m*m;
    }
    __syncthreads();
    for (int e = t; e < DC*QC; e += 256) {
        int d = e >> 4, q = e & 15;
        float lv = Lam[k*DC*QC + e];
        lamR[d*17 + q]  = lv;
        lamSc[d*17 + q] = lv * invpsiS[d];
    }
    __syncthreads();
    {   // M = I + Lam^T diag(invpsi) Lam
        int q = t >> 4, r = t & 15;
        float s0 = (q == r) ? 1.0f : 0.0f, s1 = 0.f, s2 = 0.f, s3 = 0.f;
#pragma unroll 1
        for (int d = 0; d < DC; d += 4) {
            s0 = fmaf(lamSc[(d+0)*17 + q], lamR[(d+0)*17 + r], s0);
            s1 = fmaf(lamSc[(d+1)*17 + q], lamR[(d+1)*17 + r], s1);
            s2 = fmaf(lamSc[(d+2)*17 + q], lamR[(d+2)*17 + r], s2);
            s3 = fmaf(lamSc[(d+3)*17 + q], lamR[(d+3)*17 + r], s3);
        }
        MS[q*QC + r] = (s0 + s1) + (s2 + s3);
    }
    __syncthreads();
    if (t < QC) {       // 16-lane shuffle Cholesky
        float m[QC], lrow[QC];
#pragma unroll
        for (int j = 0; j < QC; j++) m[j] = MS[t*QC + j];
#pragma unroll
        for (int j = 0; j < QC; j++) {
            float piv = __shfl(m[j], j, 16);
            float ljj = sqrtf(piv);
            float lij = m[j] / ljj;
            lrow[j] = lij;
#pragma unroll
            for (int r = j + 1; r < QC; r++)
                m[r] = fmaf(-lij, __shfl(lij, r, 16), m[r]);
        }
#pragma unroll
        for (int j = 0; j < QC; j++) LSm[t*QC + j] = lrow[j];
        invDS[t] = 1.0f / lrow[t];
        float ld = 2.0f * logf(lrow[t]);
        ld += __shfl_xor(ld, 1, 16);
        ld += __shfl_xor(ld, 2, 16);
        ld += __shfl_xor(ld, 4, 16);
        ld += __shfl_xor(ld, 8, 16);
        if (t == 0) ldS = ld;
    }
    __syncthreads();
    float g[QC];
    if (t < DC) {       // forward solve: column t of G
        float b[QC];
#pragma unroll
        for (int q = 0; q < QC; q++) b[q] = lamSc[t*17 + q];
#pragma unroll
        for (int i = 0; i < QC; i++) {
            float s = b[i];
#pragma unroll
            for (int x = 0; x < i; x++)
                s = fmaf(-LSm[i*QC + x], g[x], s);
            g[i] = s * invDS[i];
        }
        const float is2 = 0.70710678118654752f;
#pragma unroll
        for (int q = 0; q < QC; q++) {
            GT[q*129 + t] = g[q];
            btG[(k*QC + q)*DC + t] = f2bf(g[q] * is2);
        }
    }
    __syncthreads();
    if (t < QC) {       // h = G mu
        float s = 0.f;
        for (int d = 0; d < DC; d++)
            s = fmaf(GT[t*129 + d], muS[d], s);
        hS[t] = s;
        float hh = s*s;
        hh += __shfl_xor(hh, 1, 16);
        hh += __shfl_xor(hh, 2, 16);
        hh += __shfl_xor(hh, 4, 16);
        hh += __shfl_xor(hh, 8, 16);
        if (t == 0) hhS = hh;
    }
    {
        float a = lp, b2 = ipm;
#pragma unroll
        for (int off = 1; off < 64; off <<= 1) {
            a  += __shfl_xor(a, off, 64);
            b2 += __shfl_xor(b2, off, 64);
        }
        if (t == 0)  { redS[0] = a; redS[1] = b2; }
        if (t == 64) { redS[2] = a; redS[3] = b2; }
    }
    __syncthreads();
    if (t < DC) {       // w' = invpsi*mu - G^T h
        float gh = 0.f;
#pragma unroll
        for (int q = 0; q < QC; q++) gh = fmaf(g[q], hS[q], gh);
        float wp = invpsiS[t]*muS[t] - gh;
        btG[(512 + k)*DC + t] = f2bf(wp);
    }
    if (t == 0) {
        const float log2pi = 1.8378770664093453f;
        float slp = redS[0] + redS[2];
        float tv  = redS[1] + redS[3];
        c2p[k] = log_pi[k]
            - 0.5f*((float)DC*log2pi + slp + ldS + tv) + 0.5f*hhS;
    }
}

// ---------------------------------------------------------------------------
// Kernel 2: MFMA GEMM (r11 map, single-plane A+B, full-row XOR swizzle).
// 2504 blocks; yb = wg&7 (comp group of 4), xb = wg>>3 (64-row tile).
// Block = 4 waves x 16 rows x 5 N-tiles (4 G-tiles + w'-tile), 20 MFMA/wave.
// LDS = 80 rows x 256B = 20 KB; chunk ^= (row&15) -> conflict-free b128.
// lr = C2' + w'.x - 0.5 s2 + ||(G/sqrt2) x||^2.
// ---------------------------------------------------------------------------
#define LH 20480     // 80*256 bytes

__global__ __launch_bounds__(256, 4) void mfa_gemm(
    const short* __restrict__ xH, const float* __restrict__ s2g,
    const float* __restrict__ c2p, const short* __restrict__ btG,
    float* __restrict__ out)
{
    __shared__ __align__(16) char lds[LH];
    int t = threadIdx.x;
    int wg = blockIdx.x;
    int yb = wg & 7, xb = wg >> 3;

    // stage B panel: 1280 chunks, 5 per thread
    bf16x8 rh[5];
#pragma unroll
    for (int i = 0; i < 5; i++) {
        int s = t + i*256;
        int row = s >> 4, seg = s & 15;
        int gr = (row < 64) ? (yb*64 + row) : (512 + yb*4 + ((row - 64) & 3));
        rh[i] = *(const bf16x8*)(btG + gr*DC + seg*8);
    }

    int l = t & 63, w = t >> 6;
    int m16 = l & 15, g4 = l >> 4;
    int rb0 = xb*64 + w*16;

    // A fragments: fragment-major, wave-uniform clamped tile base (1KB loads)
    int tile16 = min(xb*4 + w, (NPTS >> 4) - 1);
    const short* ph = xH + (size_t)tile16*2048 + g4*128 + m16*8;
    bf16x8 aH[4];
#pragma unroll
    for (int ks = 0; ks < 4; ks++)
        aH[ks] = *(const bf16x8*)(ph + ks*512);
    float s2p = s2g[min(rb0 + m16, NPTS - 1)];

    // swizzled ds_writes: chunk ^ (row&15)
#pragma unroll
    for (int i = 0; i < 5; i++) {
        int s = t + i*256;
        int row = s >> 4, seg = s & 15;
        unsigned bo = ((unsigned)row << 8) + ((unsigned)(seg ^ (row & 15)) << 4);
        *(bf16x8*)(lds + bo) = rh[i];
    }
    __syncthreads();

    f32x4 acc[5];
#pragma unroll
    for (int i = 0; i < 5; i++) acc[i] = (f32x4){0.f, 0.f, 0.f, 0.f};
#pragma unroll
    for (int nt = 0; nt < 5; nt++) {
        int row = (nt < 4 ? nt*16 : 64) + m16;
        unsigned rbse = (unsigned)row << 8;
        unsigned sw = (unsigned)(row & 15);
#pragma unroll
        for (int ks = 0; ks < 4; ks++) {
            unsigned chunk = (unsigned)(ks*4 + g4);
            unsigned bo = rbse + ((chunk ^ sw) << 4);
            bf16x8 bh = *(const bf16x8*)(lds + bo);
            acc[nt] = __builtin_amdgcn_mfma_f32_16x16x32_bf16(aH[ks], bh, acc[nt], 0, 0, 0);
        }
    }

#pragma unroll
    for (int nt = 0; nt < 4; nt++) {
        float c2v = c2p[yb*4 + nt];
#pragma unroll
        for (int j = 0; j < 4; j++) {
            float v = acc[nt][j]*acc[nt][j];
            v += __shfl_xor(v, 1, 64);
            v += __shfl_xor(v, 2, 64);
            v += __shfl_xor(v, 4, 64);
            v += __shfl_xor(v, 8, 64);
            float pv  = __shfl(acc[4][j], (l & 48) | nt, 64);
            float s2j = __shfl(s2p, (l & 48) | (g4*4 + j), 64);
            float lr = c2v + pv - s2j + v;
            int row = rb0 + g4*4 + j;
            if (m16 == 0 && row < NPTS)
                out[(size_t)row*KC + yb*4 + nt] = lr;
        }
    }
}

// ---------------------------------------------------------------------------
// Kernel 3: in-place logsumexp normalize + log-likelihood output.
// ---------------------------------------------------------------------------
__global__ __launch_bounds__(256) void mfa_norm(float* __restrict__ out)
{
    int n = blockIdx.x * 256 + threadIdx.x;
    if (n >= NPTS) return;
    float lr[KC];
#pragma unroll
    for (int i = 0; i < 8; i++)
        *(float4*)&lr[i*4] = *(const float4*)(out + (size_t)n*KC + i*4);
    float m = -1e30f;
#pragma unroll
    for (int k = 0; k < KC; k++) m = fmaxf(m, lr[k]);
    float s = 0.0f;
#pragma unroll
    for (int k = 0; k < KC; k++) s += expf(lr[k] - m);
    float ll = m + logf(s);
#pragma unroll
    for (int k = 0; k < KC; k++) lr[k] -= ll;
#pragma unroll
    for (int i = 0; i < 8; i++)
        *(float4*)(out + (size_t)n*KC + i*4) = *(const float4*)&lr[i*4];
    out[(size_t)NPTS*KC + n] = ll;
}

extern "C" void kernel_launch(void* const* d_in, const int* in_sizes, int n_in,
                              void* d_out, int out_size, void* d_ws, size_t ws_size,
                              hipStream_t stream)
{
    const float* X       = (const float*)d_in[0];
    const float* log_pi  = (const float*)d_in[1];
    const float* mu      = (const float*)d_in[2];
    const float* Lam     = (const float*)d_in[3];
    const float* log_psi = (const float*)d_in[4];
    float* out = (float*)d_out;
    char* wsb = (char*)d_ws;
    float* c2p = (float*)(wsb + WS_C2P_B);
    short* btG = (short*)(wsb + WS_BTG_B);
    float* s2g = (float*)(wsb + WS_S2_B);
    short* xH  = (short*)(wsb + WS_XH_B);

    hipLaunchKernelGGL(mfa_prep, dim3(KC + 313), dim3(256), 0, stream,
                       X, log_pi, mu, Lam, log_psi, c2p, btG, xH, s2g);
    hipLaunchKernelGGL(mfa_gemm, dim3(2504), dim3(256), 0, stream,
                       xH, s2g, c2p, btG, out);
    hipLaunchKernelGGL(mfa_norm, dim3(79), dim3(256), 0, stream, out);
}